// Round 5
// baseline (363.332 us; speedup 1.0000x reference)
//
#include <hip/hip_runtime.h>
#include <hip/hip_bf16.h>
#include <stdint.h>

// Problem constants (B=4, T=2048, D=256, M=128, L=16, P=2048)
// fp16 low-precision path: score sigma ~4e-3 -> TAU = 0.05 (~12 sigma)
#define TAU 0.05f

typedef __attribute__((ext_vector_type(8))) _Float16 f16x8;
typedef __attribute__((ext_vector_type(4))) float f32x4;

__device__ __forceinline__ unsigned short f2h(float f) {
  _Float16 h = (_Float16)f;
  return __builtin_bit_cast(unsigned short, h);
}
__device__ __forceinline__ float h2f(unsigned short u) {
  _Float16 h = __builtin_bit_cast(_Float16, u);
  return (float)h;
}
__device__ __forceinline__ void async_copy16(const void* g, void* l) {
  __builtin_amdgcn_global_load_lds(
      (const __attribute__((address_space(1))) unsigned int*)g,
      (__attribute__((address_space(3))) unsigned int*)l, 16, 0, 0);
}

// ---------------------------------------------------------------------------
// K0: transpose+convert x -> xt[b][d][t] (fp16, K-contig); w1 -> w1t[n][k]
//     (fp16, K-contig); init logits with b2; zero per-batch job counters.
// ---------------------------------------------------------------------------
__global__ __launch_bounds__(256) void k_prep(
    const float* __restrict__ x, const float* __restrict__ w1,
    const float* __restrict__ b2,
    unsigned short* __restrict__ xt, unsigned short* __restrict__ w1t,
    float* __restrict__ logits, int* __restrict__ njobsb) {
  __shared__ float tileS[64][65];
  int bx = blockIdx.x, tid = threadIdx.x;
  if (bx == 0 && tid < 4) njobsb[tid] = 0;
  if (bx < 64) {  // logits init: 16384 floats
    int i = bx * 256 + tid;
    logits[i] = b2[i & 1];
  }
  int j = tid & 63, i0 = tid >> 6;
  if (bx < 512) {                       // x tiles: b(4) * t-tiles(32) * d-tiles(4)
    int b = bx >> 7, t6 = (bx >> 2) & 31, d6 = bx & 3;
    const float* src = x + ((size_t)b * 2048 + (size_t)t6 * 64) * 256 + d6 * 64;
    for (int i = i0; i < 64; i += 4) tileS[i][j] = src[(size_t)i * 256 + j];
    __syncthreads();
    unsigned short* dst = xt + ((size_t)b * 256 + (size_t)d6 * 64) * 2048 + t6 * 64;
    for (int r = i0; r < 64; r += 4) dst[(size_t)r * 2048 + j] = f2h(tileS[j][r]);
  } else {                              // w1 tiles: k-tiles(12) * n-tiles(4)
    int wt = bx - 512;
    int k6 = wt >> 2, n6 = wt & 3;
    const float* src = w1 + ((size_t)k6 * 64) * 256 + n6 * 64;
    for (int i = i0; i < 64; i += 4) tileS[i][j] = src[(size_t)i * 256 + j];
    __syncthreads();
    unsigned short* dst = w1t + ((size_t)n6 * 64) * 768 + k6 * 64;
    for (int r = i0; r < 64; r += 4) dst[(size_t)r * 768 + j] = f2h(tileS[j][r]);
  }
}

// ---------------------------------------------------------------------------
// K1: [head;tail] @ x -> hrep16/trep16 (fp16 out, fp32 accum)
// Block 64 rows x 128 cols, 8 waves (wave tile 16x64), interval 64 k, dbuf.
// grid 512 = 2 blocks/CU: cross-block overlap hides the barrier vmcnt drain.
// LDS chunk convention: slot s of row r holds k8 = s ^ (r&7) (16B chunks).
// A: fp32 loaded k-contig (8 rows x 256 B per instr), cvt in reg, ds_write.
// B: global_load_lds with swizzle applied to the GLOBAL address (lane-linear
// LDS dst), coalesced within 256 B windows.
// ---------------------------------------------------------------------------
__global__ __launch_bounds__(512, 4) void k_gemm_rep(
    const float* __restrict__ head, const float* __restrict__ tail,
    const unsigned short* __restrict__ xt,
    unsigned short* __restrict__ hrep16, unsigned short* __restrict__ trep16) {
  __shared__ unsigned short As[2][4096];  // 64 rows * 8 slots * 8 halves
  __shared__ unsigned short Bs[2][8192];  // 128 cols * 8 slots
  int bx = blockIdx.x;
  int rt = bx >> 1, ntile = bx & 1;
  int g0 = rt * 64;                      // 0..16383
  int isTail = g0 >> 13;
  int local = g0 & 8191;                 // b*2048 + p
  int b = local >> 11;
  const float* Asrc = (isTail ? tail : head) + (size_t)local * 2048;
  unsigned short* Crep = isTail ? trep16 : hrep16;
  const unsigned short* Bsrc = xt + ((size_t)b * 256 + ntile * 128) * 2048;

  int tid = threadIdx.x, lane = tid & 63, w = tid >> 6;  // w 0..7
  int l15 = lane & 15, l4 = lane >> 4;
  int msub = w & 3, nsub = w >> 2;

  // A staging: wave w rows 8w..8w+7; lane: arow = 8w+(lane>>3), j = lane&7
  int arow = 8 * w + (lane >> 3), aj = lane & 7;
  const float* aptr = Asrc + (size_t)arow * 2048 + aj * 8;
  int awc = (arow * 8 + (aj ^ (arow & 7))) * 8;  // ushort offset

  // fragment offsets (ushort index)
  int acOf[2];
#pragma unroll
  for (int s = 0; s < 2; ++s) {
    int row = msub * 16 + l15, k8 = s * 4 + l4;
    acOf[s] = (row * 8 + (k8 ^ (row & 7))) * 8;
  }
  int bcOf[2][4];
#pragma unroll
  for (int s = 0; s < 2; ++s)
#pragma unroll
    for (int ct = 0; ct < 4; ++ct) {
      int col = nsub * 64 + ct * 16 + l15, k8 = s * 4 + l4;
      bcOf[s][ct] = (col * 8 + (k8 ^ (col & 7))) * 8;
    }

  auto stageB = [&](int iv, unsigned short* buf) {
#pragma unroll
    for (int a = 0; a < 2; ++a) {
      int e = 2 * w + a;
      int colofs = lane >> 3, j = lane & 7;
      int col = e * 8 + colofs;
      const unsigned short* src =
          Bsrc + (size_t)col * 2048 + iv * 64 + (j ^ colofs) * 8;
      async_copy16(src, buf + ((size_t)e * 64 + lane) * 8);
    }
  };
  auto loadA = [&](float4* v, int iv) {
    const float* p = aptr + iv * 64;
    v[0] = *(const float4*)p;
    v[1] = *(const float4*)(p + 4);
  };
  auto packA = [&](const float4* v, unsigned short* buf) {
    f16x8 pk;
    pk[0] = (_Float16)v[0].x; pk[1] = (_Float16)v[0].y;
    pk[2] = (_Float16)v[0].z; pk[3] = (_Float16)v[0].w;
    pk[4] = (_Float16)v[1].x; pk[5] = (_Float16)v[1].y;
    pk[6] = (_Float16)v[1].z; pk[7] = (_Float16)v[1].w;
    *(f16x8*)(buf + awc) = pk;
  };

  f32x4 acc[4];
#pragma unroll
  for (int ct = 0; ct < 4; ++ct) acc[ct] = (f32x4){0.f, 0.f, 0.f, 0.f};

  float4 avW[2], avF[2];
  loadA(avW, 0);
  stageB(0, Bs[0]);
  packA(avW, As[0]);
  loadA(avW, 1);
  __syncthreads();

  for (int it = 0; it < 32; ++it) {
    int cur = it & 1, nxt = cur ^ 1;
    if (it < 31) stageB(it + 1, Bs[nxt]);
    if (it < 30) loadA(avF, it + 2);
#pragma unroll
    for (int s = 0; s < 2; ++s) {
      f16x8 a = *(const f16x8*)&As[cur][acOf[s]];
#pragma unroll
      for (int ct = 0; ct < 4; ++ct) {
        f16x8 bf = *(const f16x8*)&Bs[cur][bcOf[s][ct]];
        acc[ct] = __builtin_amdgcn_mfma_f32_16x16x32_f16(a, bf, acc[ct], 0, 0, 0);
      }
    }
    if (it < 31) {
      packA(avW, As[nxt]);
      avW[0] = avF[0]; avW[1] = avF[1];
    }
    __syncthreads();
  }

  // epilogue: C layout col=lane&15, row=(lane>>4)*4+i; store fp16
  int rowb = local + msub * 16 + l4 * 4;
  int colb = ntile * 128 + nsub * 64 + l15;
#pragma unroll
  for (int ct = 0; ct < 4; ++ct)
#pragma unroll
    for (int i = 0; i < 4; ++i)
      Crep[(size_t)(rowb + i) * 256 + colb + ct * 16] = f2h(acc[ct][i]);
}

// ---------------------------------------------------------------------------
// K2pre: featp[p][d] = h*t (fp16) — h,t slabs are read directly from reps.
// ---------------------------------------------------------------------------
__global__ __launch_bounds__(256) void k_feat(
    const unsigned short* __restrict__ hrep16,
    const unsigned short* __restrict__ trep16,
    unsigned short* __restrict__ featp) {
  int gid = blockIdx.x * 256 + threadIdx.x;  // 0..524287, 4 elems each
  size_t o = (size_t)gid * 4;
  ushort4 h4 = *(const ushort4*)&hrep16[o];
  ushort4 t4 = *(const ushort4*)&trep16[o];
  ushort4 c;
  c.x = f2h(h2f(h4.x) * h2f(t4.x)); c.y = f2h(h2f(h4.y) * h2f(t4.y));
  c.z = f2h(h2f(h4.z) * h2f(t4.z)); c.w = f2h(h2f(h4.w) * h2f(t4.w));
  *(ushort4*)&featp[o] = c;
}

// ---------------------------------------------------------------------------
// K2: relu([h|t|h*t] @ w1 + b1) @ w2 + b2 -> logits (fused, atomicAdd).
// Block 64 rows x 64 cols, 8 waves (16x32), interval 64 k (12 ivs), dbuf,
// grid 512 = 2 blocks/CU. A-source per interval: hrep16 / trep16 / featp.
// All staging via swizzled global_load_lds (coalesced).
// ---------------------------------------------------------------------------
__global__ __launch_bounds__(512, 4) void k_gemm_mlp(
    const unsigned short* __restrict__ hrep16,
    const unsigned short* __restrict__ trep16,
    const unsigned short* __restrict__ featp,
    const unsigned short* __restrict__ w1t,
    const float* __restrict__ b1, const float* __restrict__ w2,
    float* __restrict__ logits) {
  __shared__ unsigned short As[2][4096];  // 64 rows * 8 slots
  __shared__ unsigned short Bs[2][4096];  // 64 cols * 8 slots
  int bx = blockIdx.x;
  int rt = bx >> 2, ntile = bx & 3;
  int row0 = rt * 64;
  int tid = threadIdx.x, lane = tid & 63, w = tid >> 6;
  int l15 = lane & 15, l4 = lane >> 4;
  int msub = w & 3, nsub = w >> 2;

  int acOf[2];
#pragma unroll
  for (int s = 0; s < 2; ++s) {
    int row = msub * 16 + l15, k8 = s * 4 + l4;
    acOf[s] = (row * 8 + (k8 ^ (row & 7))) * 8;
  }
  int bcOf[2][2];
#pragma unroll
  for (int s = 0; s < 2; ++s)
#pragma unroll
    for (int ct = 0; ct < 2; ++ct) {
      int col = nsub * 32 + ct * 16 + l15, k8 = s * 4 + l4;
      bcOf[s][ct] = (col * 8 + (k8 ^ (col & 7))) * 8;
    }

  int rowofs = lane >> 3, j7 = lane & 7;
  auto stageA = [&](int iv, unsigned short* buf) {
    const unsigned short* s; int ko;
    if (iv < 4)      { s = hrep16; ko = iv * 64; }
    else if (iv < 8) { s = trep16; ko = (iv - 4) * 64; }
    else             { s = featp;  ko = (iv - 8) * 64; }
    const unsigned short* src =
        s + (size_t)(row0 + w * 8 + rowofs) * 256 + ko + (j7 ^ rowofs) * 8;
    async_copy16(src, buf + ((size_t)w * 64 + lane) * 8);
  };
  auto stageBm = [&](int iv, unsigned short* buf) {
    const unsigned short* src =
        w1t + (size_t)(ntile * 64 + w * 8 + rowofs) * 768 + iv * 64 + (j7 ^ rowofs) * 8;
    async_copy16(src, buf + ((size_t)w * 64 + lane) * 8);
  };

  f32x4 acc[2];
  acc[0] = (f32x4){0.f, 0.f, 0.f, 0.f};
  acc[1] = (f32x4){0.f, 0.f, 0.f, 0.f};

  stageA(0, As[0]);
  stageBm(0, Bs[0]);
  __syncthreads();

  for (int it = 0; it < 12; ++it) {
    int cur = it & 1, nxt = cur ^ 1;
    if (it < 11) { stageA(it + 1, As[nxt]); stageBm(it + 1, Bs[nxt]); }
#pragma unroll
    for (int s = 0; s < 2; ++s) {
      f16x8 a = *(const f16x8*)&As[cur][acOf[s]];
#pragma unroll
      for (int ct = 0; ct < 2; ++ct) {
        f16x8 bf = *(const f16x8*)&Bs[cur][bcOf[s][ct]];
        acc[ct] = __builtin_amdgcn_mfma_f32_16x16x32_f16(a, bf, acc[ct], 0, 0, 0);
      }
    }
    __syncthreads();
  }

  // epilogue: relu(+b1), dot w2 cols, reduce over 16-lane col group
  float bv[2], w20[2], w21[2];
#pragma unroll
  for (int ct = 0; ct < 2; ++ct) {
    int col = ntile * 64 + nsub * 32 + ct * 16 + l15;
    bv[ct] = b1[col]; w20[ct] = w2[col * 2]; w21[ct] = w2[col * 2 + 1];
  }
#pragma unroll
  for (int i = 0; i < 4; ++i) {
    float s0 = 0.f, s1 = 0.f;
#pragma unroll
    for (int ct = 0; ct < 2; ++ct) {
      float r = fmaxf(acc[ct][i] + bv[ct], 0.f);
      s0 += r * w20[ct]; s1 += r * w21[ct];
    }
#pragma unroll
    for (int off = 1; off < 16; off <<= 1) {
      s0 += __shfl_xor(s0, off); s1 += __shfl_xor(s1, off);
    }
    if (l15 == 0) {
      int row = row0 + msub * 16 + l4 * 4 + i;
      atomicAdd(&logits[row * 2], s0);
      atomicAdd(&logits[row * 2 + 1], s1);
    }
  }
}

// ---------------------------------------------------------------------------
// K3b: per-mention top-1 + uncertainty set; emit per-batch refine jobs
// ---------------------------------------------------------------------------
__global__ void k_select(const float* __restrict__ logits, int* __restrict__ idxv,
                         float* __restrict__ mval, int* __restrict__ cmask,
                         int* __restrict__ njobsb, int* __restrict__ jobsb) {
  int q = blockIdx.x * 256 + threadIdx.x;
  if (q >= 512) return;
  int b = q >> 7;
  int base = q * 16;
  float s[16];
#pragma unroll
  for (int i = 0; i < 16; ++i) s[i] = logits[(size_t)(base + i) * 2 + 1];
  float best = s[0]; int bi = 0;
#pragma unroll
  for (int i = 1; i < 16; ++i) if (s[i] > best) { best = s[i]; bi = i; }
  int mask = 0, cnt = 0;
#pragma unroll
  for (int i = 0; i < 16; ++i) if (s[i] > best - TAU) { mask |= 1 << i; ++cnt; }
  idxv[q] = bi; mval[q] = best;
  if (cnt > 1) {
    cmask[q] = mask;
    for (int i = 0; i < 16; ++i)
      if ((mask >> i) & 1) {
        int idx = atomicAdd(&njobsb[b], 1);
        jobsb[b * 2048 + idx] = base + i;
      }
  } else cmask[q] = 0;
}

// ---------------------------------------------------------------------------
// K3c: fp32 exact score recompute; 8 jobs share one x pass (t-major LDS rows,
// broadcast reads) and one w1 pass. Work items flattened across batches.
// ---------------------------------------------------------------------------
__global__ __launch_bounds__(1024) void k_refine(
    const int* __restrict__ njobsb, const int* __restrict__ jobsb,
    const float* __restrict__ head, const float* __restrict__ tail,
    const float* __restrict__ x, const float* __restrict__ w1,
    const float* __restrict__ b1, const float* __restrict__ w2,
    const float* __restrict__ b2, float* __restrict__ refined) {
  __shared__ float hT[2048 * 8];   // [t][j] 64 KB  (overlaid by featL later)
  __shared__ float tT[2048 * 8];   // 64 KB
  __shared__ float red[1024], red2[1024];
  __shared__ int jc[8];
  float* featL = hT;               // [8][768] fp32 overlay

  int tid = threadIdx.x;
  int d = tid & 255, seg = tid >> 8;
  int nch[4], tot = 0;
#pragma unroll
  for (int b = 0; b < 4; ++b) { int n = njobsb[b]; nch[b] = (n + 7) >> 3; tot += nch[b]; }

  for (int g = blockIdx.x; g < tot; g += gridDim.x) {
    int b = 0, c = g;
    while (c >= nch[b]) { c -= nch[b]; ++b; }
    int nj = njobsb[b];
    int j0 = c * 8, jn = min(8, nj - j0);
    if (tid < 8) jc[tid] = (tid < jn) ? jobsb[b * 2048 + j0 + tid] : -1;
    __syncthreads();
    for (int j = 0; j < jn; ++j) {
      int p = jc[j] & 2047;
      const float* hr = head + ((size_t)(b * 2048 + p)) * 2048;
      const float* tr = tail + ((size_t)(b * 2048 + p)) * 2048;
      for (int t = tid; t < 2048; t += 1024) {
        hT[t * 8 + j] = hr[t];
        tT[t * 8 + j] = tr[t];
      }
    }
    __syncthreads();
    // dots: thread (d, seg); x coalesced over d; LDS rows broadcast
    float ha[8], ta[8];
#pragma unroll
    for (int j = 0; j < 8; ++j) { ha[j] = 0.f; ta[j] = 0.f; }
    const float* xb = x + ((size_t)b * 2048) * 256 + d;
    for (int t = seg * 512; t < seg * 512 + 512; ++t) {
      float xv = xb[(size_t)t * 256];
      float4 h0 = *(const float4*)&hT[t * 8], h1 = *(const float4*)&hT[t * 8 + 4];
      float4 t0 = *(const float4*)&tT[t * 8], t1 = *(const float4*)&tT[t * 8 + 4];
      ha[0] += h0.x * xv; ha[1] += h0.y * xv; ha[2] += h0.z * xv; ha[3] += h0.w * xv;
      ha[4] += h1.x * xv; ha[5] += h1.y * xv; ha[6] += h1.z * xv; ha[7] += h1.w * xv;
      ta[0] += t0.x * xv; ta[1] += t0.y * xv; ta[2] += t0.z * xv; ta[3] += t0.w * xv;
      ta[4] += t1.x * xv; ta[5] += t1.y * xv; ta[6] += t1.z * xv; ta[7] += t1.w * xv;
    }
    __syncthreads();  // hT/tT reads done -> featL overlay safe
    for (int j = 0; j < jn; ++j) {
      red[tid] = ha[j]; red2[tid] = ta[j];
      __syncthreads();
      if (seg == 0) {
        float fh = red[d] + red[256 + d] + red[512 + d] + red[768 + d];
        float ft = red2[d] + red2[256 + d] + red2[512 + d] + red2[768 + d];
        featL[j * 768 + d] = fh;
        featL[j * 768 + 256 + d] = ft;
        featL[j * 768 + 512 + d] = fh * ft;
      }
      __syncthreads();
    }
    // MLP: w1 read once, shared by 8 jobs
    float hacc[8];
#pragma unroll
    for (int j = 0; j < 8; ++j) hacc[j] = 0.f;
    for (int ii = seg * 192; ii < seg * 192 + 192; ++ii) {
      float wv = w1[(size_t)ii * 256 + d];
#pragma unroll
      for (int j = 0; j < 8; ++j) hacc[j] += featL[j * 768 + ii] * wv;
    }
    for (int j = 0; j < jn; ++j) {
      red[tid] = hacc[j];
      __syncthreads();
      if (seg == 0) {
        float h = b1[d] + red[d] + red[256 + d] + red[512 + d] + red[768 + d];
        h = fmaxf(h, 0.f);
        float v = h * w2[d * 2 + 1];
        // wave-level reduce (4 waves in seg 0), then cross-wave via red2
        for (int off = 32; off; off >>= 1) v += __shfl_xor(v, off);
        if ((tid & 63) == 0) red2[tid >> 6] = v;
      }
      __syncthreads();
      if (tid == 0)
        refined[jc[j]] = red2[0] + red2[1] + red2[2] + red2[3] + b2[1];
      __syncthreads();
    }
  }
}

// ---------------------------------------------------------------------------
// K4a: rep_m[q][d] = tail_rep16[q*16+argmax][d] * max_val
// ---------------------------------------------------------------------------
__global__ __launch_bounds__(256) void k_repm(
    const int* __restrict__ idxv, const float* __restrict__ mval,
    const int* __restrict__ cmask, const float* __restrict__ refined,
    const unsigned short* __restrict__ trep16, float* __restrict__ repm) {
  int q = blockIdx.x, d = threadIdx.x;
  int mask = cmask[q]; int bi; float v;
  if (mask) {
    bi = -1; v = -1e30f;
    for (int i = 0; i < 16; ++i)
      if ((mask >> i) & 1) { float s = refined[q * 16 + i]; if (s > v) { v = s; bi = i; } }
  } else { bi = idxv[q]; v = mval[q]; }
  repm[(size_t)q * 256 + d] = h2f(trep16[((size_t)q * 16 + bi) * 256 + d]) * v;
}

// ---------------------------------------------------------------------------
// K4b: out[b][t][d] = x + sum_m cmp[b][m][t] * rep_m[b][m][d]  (512 blocks)
// ---------------------------------------------------------------------------
__global__ __launch_bounds__(256) void k_merge(
    const float* __restrict__ cmp, const float* __restrict__ repm,
    const float* __restrict__ x, float* __restrict__ out) {
  __shared__ float cl[128 * 16];
  int bx = blockIdx.x, b = bx >> 7, t0 = (bx & 127) * 16;
  int tid = threadIdx.x;
#pragma unroll
  for (int it = 0; it < 2; ++it) {
    int f = it * 256 + tid;
    int row = f >> 2, c4 = (f & 3) * 4;
    *(float4*)&cl[row * 16 + c4] =
        *(const float4*)&cmp[((size_t)(b * 128 + row)) * 2048 + t0 + c4];
  }
  __syncthreads();
  float acc[16];
#pragma unroll
  for (int i = 0; i < 16; ++i) acc[i] = 0.f;
  int d = tid;
  for (int m = 0; m < 128; ++m) {
    float rv = repm[(size_t)(b * 128 + m) * 256 + d];
    const float4* c4p = (const float4*)&cl[m * 16];
#pragma unroll
    for (int jj = 0; jj < 4; ++jj) {
      float4 c = c4p[jj];
      acc[jj * 4] += c.x * rv; acc[jj * 4 + 1] += c.y * rv;
      acc[jj * 4 + 2] += c.z * rv; acc[jj * 4 + 3] += c.w * rv;
    }
  }
  const float* xb = x + ((size_t)(b * 2048 + t0)) * 256 + d;
  float* ob = out + ((size_t)(b * 2048 + t0)) * 256 + d;
#pragma unroll
  for (int tt = 0; tt < 16; ++tt) ob[(size_t)tt * 256] = xb[(size_t)tt * 256] + acc[tt];
}

// ---------------------------------------------------------------------------
// K5: masked KLDiv mean loss (single block)
// ---------------------------------------------------------------------------
__global__ __launch_bounds__(1024) void k_loss(
    const float* __restrict__ logits, const float* __restrict__ lab,
    const unsigned char* __restrict__ mask, float* __restrict__ out_loss) {
  __shared__ float rs[1024], rc[1024];
  int tid = threadIdx.x;
  float sum = 0.f, cnt = 0.f;
  for (int p = tid; p < 8192; p += 1024) {
    float l0 = logits[(size_t)p * 2], l1 = logits[(size_t)p * 2 + 1];
    float a0 = lab[(size_t)p * 2], a1 = lab[(size_t)p * 2 + 1];
    float mx = fmaxf(l0, l1);
    float lse = mx + logf(expf(l0 - mx) + expf(l1 - mx));
    float pw = 0.f;
    if (a0 > 0.f) pw += a0 * logf(fmaxf(a0, 1e-38f));
    if (a1 > 0.f) pw += a1 * logf(fmaxf(a1, 1e-38f));
    pw -= a0 * (l0 - lse) + a1 * (l1 - lse);
    if (mask[p]) { sum += pw; cnt += 1.f; }
  }
  rs[tid] = sum; rc[tid] = cnt;
  __syncthreads();
  for (int s = 512; s > 0; s >>= 1) {
    if (tid < s) { rs[tid] += rs[tid + s]; rc[tid] += rc[tid + s]; }
    __syncthreads();
  }
  if (tid == 0) *out_loss = rs[0] / (rc[0] * 2.0f);
}

// ---------------------------------------------------------------------------
extern "C" void kernel_launch(void* const* d_in, const int* in_sizes, int n_in,
                              void* d_out, int out_size, void* d_ws, size_t ws_size,
                              hipStream_t stream) {
  (void)in_sizes; (void)n_in; (void)out_size; (void)ws_size;
  const float* head = (const float*)d_in[0];
  const float* tail = (const float*)d_in[1];
  // d_in[2] = lens (uniform L=16) -- unused
  const float* x = (const float*)d_in[3];
  const float* cmp = (const float*)d_in[4];
  const float* lab = (const float*)d_in[5];
  const unsigned char* lmask = (const unsigned char*)d_in[6];
  const float* w1 = (const float*)d_in[7];
  const float* b1 = (const float*)d_in[8];
  const float* w2 = (const float*)d_in[9];
  const float* b2 = (const float*)d_in[10];
  float* out = (float*)d_out;

  char* ws = (char*)d_ws;
  size_t off = 0;
  auto alloc = [&](size_t bytes) -> void* {
    void* p = ws + off; off += (bytes + 255) & ~(size_t)255; return p;
  };
  unsigned short* xt = (unsigned short*)alloc(4ull * 256 * 2048 * 2);
  unsigned short* w1t = (unsigned short*)alloc(256ull * 768 * 2);
  unsigned short* hrep16 = (unsigned short*)alloc(8192ull * 256 * 2);
  unsigned short* trep16 = (unsigned short*)alloc(8192ull * 256 * 2);
  unsigned short* featp = (unsigned short*)alloc(8192ull * 256 * 2);
  float* logits = (float*)alloc(8192ull * 2 * 4);
  float* refined = (float*)alloc(8192ull * 4);
  int* idxv = (int*)alloc(512 * 4);
  float* mvalv = (float*)alloc(512 * 4);
  int* cmaskv = (int*)alloc(512 * 4);
  int* njobsb = (int*)alloc(256);
  int* jobsb = (int*)alloc(4 * 2048 * 4);
  float* repm = (float*)alloc(512ull * 256 * 4);

  k_prep<<<560, 256, 0, stream>>>(x, w1, b2, xt, w1t, logits, njobsb);
  k_gemm_rep<<<512, 512, 0, stream>>>(head, tail, xt, hrep16, trep16);
  k_feat<<<2048, 256, 0, stream>>>(hrep16, trep16, featp);
  k_gemm_mlp<<<512, 512, 0, stream>>>(hrep16, trep16, featp, w1t, b1, w2, logits);
  k_select<<<2, 256, 0, stream>>>(logits, idxv, mvalv, cmaskv, njobsb, jobsb);
  k_refine<<<256, 1024, 0, stream>>>(njobsb, jobsb, head, tail, x, w1, b1, w2, b2, refined);
  k_repm<<<512, 256, 0, stream>>>(idxv, mvalv, cmaskv, refined, trep16, repm);
  k_merge<<<512, 256, 0, stream>>>(cmp, repm, x, out);
  k_loss<<<1, 1024, 0, stream>>>(logits, lab, lmask, out + 4ull * 2048 * 256);
}